// Round 6
// baseline (554.011 us; speedup 1.0000x reference)
//
#include <hip/hip_runtime.h>

#define DEVINL __device__ __forceinline__

typedef __attribute__((ext_vector_type(4))) float f32x4;

static constexpr int SS = 12288;   // S = NKV
static constexpr float QKS = 0.17677669529663687f;  // 1/sqrt(32)

DEVINL f32x4 f32x4_zero() { f32x4 z; z[0]=0.f; z[1]=0.f; z[2]=0.f; z[3]=0.f; return z; }

DEVINL f32x4 mfma8(long long a, long long b, f32x4 c) {
  return __builtin_amdgcn_mfma_f32_16x16x32_fp8_fp8(a, b, c, 0, 0, 0);
}

// pack 4 floats -> 4 fp8 e4m3 bytes (RNE, saturating)
DEVINL unsigned pk4_fp8(float a, float b, float c, float d) {
#if __has_builtin(__builtin_amdgcn_cvt_pk_fp8_f32)
  int r = 0;
  r = __builtin_amdgcn_cvt_pk_fp8_f32(a, b, r, false);
  r = __builtin_amdgcn_cvt_pk_fp8_f32(c, d, r, true);
  return (unsigned)r;
#else
  unsigned r;
  asm("v_cvt_pk_fp8_f32 %0, %1, %2" : "=v"(r) : "v"(a), "v"(b));
  asm("v_cvt_pk_fp8_f32 %0, %1, %2 op_sel:[0,0,1]" : "+v"(r) : "v"(c), "v"(d));
  return r;
#endif
}
DEVINL unsigned char f2fp8(float x) { return (unsigned char)(pk4_fp8(x, x, x, x) & 0xFF); }

// swizzled byte offset into a [16 q][128 c] fp8 LDS tile: 8B-chunk ^= (q&15)
DEVINL int xoff(int q, int c) {
  return q * 128 + ((((c >> 3) ^ q) & 15) << 3) + (c & 7);
}
// intra-wave LDS fence
DEVINL void wave_sync() {
  asm volatile("s_waitcnt lgkmcnt(0)" ::: "memory");
  __builtin_amdgcn_sched_barrier(0);
}
DEVINL float gelu_f(float x) {  // tanh-approximate gelu (jax default)
  float u = 0.7978845608028654f * (x + 0.044715f * x * x * x);
  float t = 1.0f - 2.0f / (__expf(2.0f * u) + 1.0f);
  return 0.5f * x * (1.0f + t);
}

// ---------------------------------------------------------------------------
// Kernel 0: repack six 128x128 fp32 weights into fp8 MFMA A-fragment order
// (A = W^T). addr = mat*16384 + half*8192 + (mt*64+l)*16 + ktl*8 + i,
// kt = half*2+ktl, holds W[kt*32+(l>>4)*8+i][mt*16+(l&15)].
// ---------------------------------------------------------------------------
__global__ void prep_weights(const float* __restrict__ w0, const float* __restrict__ w1,
                             const float* __restrict__ w2, const float* __restrict__ w3,
                             const float* __restrict__ w4, const float* __restrict__ w5,
                             unsigned char* __restrict__ wfrag) {
  int gid = blockIdx.x * 256 + threadIdx.x;   // < 98304
  int i   = gid & 7;
  int ktl = (gid >> 3) & 1;
  int l   = (gid >> 4) & 63;
  int mt  = (gid >> 10) & 7;
  int hf  = (gid >> 13) & 1;
  int mat = gid >> 14;
  const float* W = (mat == 0) ? w0 : (mat == 1) ? w1 : (mat == 2) ? w2
                 : (mat == 3) ? w3 : (mat == 4) ? w4 : w5;
  int kt = hf * 2 + ktl;
  int k = kt * 32 + (l >> 4) * 8 + i;
  int c = mt * 16 + (l & 15);
  wfrag[gid] = f2fp8(W[k * 128 + c]);
}

// ---------------------------------------------------------------------------
// Kernel 1: kv = LN(x_kv) @ Wkv + bkv  -> fp8 workspace [24576][256]
// ---------------------------------------------------------------------------
__global__ __launch_bounds__(256) void kv_proj(
    const float* __restrict__ xkv, const float* __restrict__ lns,
    const float* __restrict__ lnb, const float* __restrict__ Wkv,
    const float* __restrict__ bkv, unsigned char* __restrict__ kvout) {
  __shared__ float y[16][132];
  const int tid = threadIdx.x;
  const size_t rb = (size_t)blockIdx.x * 16;

  {
    int r = tid >> 4, p = tid & 15;
    const float* xr = xkv + (rb + r) * 128 + p * 8;
    float v[8];
    float sum = 0.f, sq = 0.f;
#pragma unroll
    for (int i = 0; i < 2; ++i) {
      float4 q4 = *(const float4*)(xr + i * 4);
      v[i*4+0]=q4.x; v[i*4+1]=q4.y; v[i*4+2]=q4.z; v[i*4+3]=q4.w;
      sum += q4.x + q4.y + q4.z + q4.w;
      sq  += q4.x*q4.x + q4.y*q4.y + q4.z*q4.z + q4.w*q4.w;
    }
    sum += __shfl_xor(sum, 1, 16); sum += __shfl_xor(sum, 2, 16);
    sum += __shfl_xor(sum, 4, 16); sum += __shfl_xor(sum, 8, 16);
    sq  += __shfl_xor(sq, 1, 16);  sq  += __shfl_xor(sq, 2, 16);
    sq  += __shfl_xor(sq, 4, 16);  sq  += __shfl_xor(sq, 8, 16);
    float mu = sum * (1.0f/128.f);
    float rs = rsqrtf(sq * (1.0f/128.f) - mu*mu + 1e-5f);
#pragma unroll
    for (int i = 0; i < 8; ++i) {
      int c = p * 8 + i;
      y[r][c] = (v[i] - mu) * rs * lns[c] + lnb[c];
    }
  }
  __syncthreads();

  const int c2 = tid;
  float acc[16];
#pragma unroll
  for (int r = 0; r < 16; ++r) acc[r] = 0.f;
  for (int c = 0; c < 128; c += 4) {
    float w0 = Wkv[(c+0)*256 + c2];
    float w1 = Wkv[(c+1)*256 + c2];
    float w2 = Wkv[(c+2)*256 + c2];
    float w3 = Wkv[(c+3)*256 + c2];
#pragma unroll
    for (int r = 0; r < 16; ++r) {
      float4 yv = *(const float4*)&y[r][c];
      acc[r] += yv.x*w0 + yv.y*w1 + yv.z*w2 + yv.w*w3;
    }
  }
  float bb = bkv[c2];
#pragma unroll
  for (int r = 0; r < 16; ++r)
    kvout[(rb + r) * 256 + c2] = f2fp8(acc[r] + bb);
}

// ---------------------------------------------------------------------------
// mmF: per-wave flipped 16x128 @ 128x128 (A = W^T fp8 from LDS, B = act fp8).
// Output: lane (lo=q, g) holds out[q][c'=mt*16+g*4+e].
// MODE 0: +bias -> X. MODE 1: +bias, gelu -> X. MODE 4: *QKS -> X.
// ---------------------------------------------------------------------------
template <int MODE>
DEVINL void mmF(unsigned char* X, const unsigned char* Wm_,
                const float* __restrict__ bias, int lo, int g, int l) {
  long long bfr[4];
#pragma unroll
  for (int kt = 0; kt < 4; ++kt)
    bfr[kt] = *(const long long*)(X + xoff(lo, kt * 32 + g * 8));
  f32x4 acc[8];
#pragma unroll
  for (int mt = 0; mt < 8; ++mt) {
    ulonglong2 a01 = *(const ulonglong2*)(Wm_ + (mt * 64 + l) * 16);
    ulonglong2 a23 = *(const ulonglong2*)(Wm_ + 8192 + (mt * 64 + l) * 16);
    f32x4 a = f32x4_zero();
    a = mfma8((long long)a01.x, bfr[0], a);
    a = mfma8((long long)a01.y, bfr[1], a);
    a = mfma8((long long)a23.x, bfr[2], a);
    a = mfma8((long long)a23.y, bfr[3], a);
    acc[mt] = a;
  }
  wave_sync();
#pragma unroll
  for (int mt = 0; mt < 8; ++mt) {
    int c0 = mt * 16 + g * 4;
    float v0 = acc[mt][0], v1 = acc[mt][1], v2 = acc[mt][2], v3 = acc[mt][3];
    if (MODE == 4) { v0 *= QKS; v1 *= QKS; v2 *= QKS; v3 *= QKS; }
    else {
      float4 b4 = *(const float4*)(bias + c0);
      v0 += b4.x; v1 += b4.y; v2 += b4.z; v3 += b4.w;
    }
    if (MODE == 1) { v0 = gelu_f(v0); v1 = gelu_f(v1); v2 = gelu_f(v2); v3 = gelu_f(v3); }
    *(unsigned*)(X + xoff(lo, c0)) = pk4_fp8(v0, v1, v2, v3);
  }
}

// x2 = xq + gamma*(ao @ Wo + b_out) -> x2 regs (fp32), no LDS write
DEVINL void mmF_x2(unsigned char* X, const unsigned char* Wm_,
                   const float* __restrict__ bias, const float* __restrict__ xqw,
                   const float* __restrict__ gm, f32x4* x2, int lo, int g, int l) {
  long long bfr[4];
#pragma unroll
  for (int kt = 0; kt < 4; ++kt)
    bfr[kt] = *(const long long*)(X + xoff(lo, kt * 32 + g * 8));
#pragma unroll
  for (int mt = 0; mt < 8; ++mt) {
    ulonglong2 a01 = *(const ulonglong2*)(Wm_ + (mt * 64 + l) * 16);
    ulonglong2 a23 = *(const ulonglong2*)(Wm_ + 8192 + (mt * 64 + l) * 16);
    f32x4 a = f32x4_zero();
    a = mfma8((long long)a01.x, bfr[0], a);
    a = mfma8((long long)a01.y, bfr[1], a);
    a = mfma8((long long)a23.x, bfr[2], a);
    a = mfma8((long long)a23.y, bfr[3], a);
    int c0 = mt * 16 + g * 4;
    float4 b4 = *(const float4*)(bias + c0);
    float4 g4 = *(const float4*)(gm + c0);
    float4 x4 = *(const float4*)(xqw + lo * 128 + c0);
    f32x4 v;
    v[0] = x4.x + g4.x * (a[0] + b4.x);
    v[1] = x4.y + g4.y * (a[1] + b4.y);
    v[2] = x4.z + g4.z * (a[2] + b4.z);
    v[3] = x4.w + g4.w * (a[3] + b4.w);
    x2[mt] = v;
  }
}

// final: m = g1 @ W2 + b2; out = x2 + gmlp*m -> global float4
DEVINL void mmF_out(unsigned char* X, const unsigned char* Wm_,
                    const float* __restrict__ bias, const float* __restrict__ gp,
                    const f32x4* x2, float* __restrict__ outw, int lo, int g, int l) {
  long long bfr[4];
#pragma unroll
  for (int kt = 0; kt < 4; ++kt)
    bfr[kt] = *(const long long*)(X + xoff(lo, kt * 32 + g * 8));
#pragma unroll
  for (int mt = 0; mt < 8; ++mt) {
    ulonglong2 a01 = *(const ulonglong2*)(Wm_ + (mt * 64 + l) * 16);
    ulonglong2 a23 = *(const ulonglong2*)(Wm_ + 8192 + (mt * 64 + l) * 16);
    f32x4 a = f32x4_zero();
    a = mfma8((long long)a01.x, bfr[0], a);
    a = mfma8((long long)a01.y, bfr[1], a);
    a = mfma8((long long)a23.x, bfr[2], a);
    a = mfma8((long long)a23.y, bfr[3], a);
    int c0 = mt * 16 + g * 4;
    float4 b4 = *(const float4*)(bias + c0);
    float4 p4 = *(const float4*)(gp + c0);
    float4 o;
    o.x = x2[mt][0] + p4.x * (a[0] + b4.x);
    o.y = x2[mt][1] + p4.y * (a[1] + b4.y);
    o.z = x2[mt][2] + p4.z * (a[2] + b4.z);
    o.w = x2[mt][3] + p4.w * (a[3] + b4.w);
    *(float4*)(outw + lo * 128 + c0) = o;
  }
}

// ---------------------------------------------------------------------------
// Kernel 2: fused main. 12 waves/block, all 6 fp8 weights LDS-resident (96KB),
// one barrier total; each wave autonomously processes 2 s-units.
// ---------------------------------------------------------------------------
__global__ __launch_bounds__(768, 3) void fused_main(
    const float* __restrict__ xq, const int* __restrict__ nh_idx,
    const unsigned char* __restrict__ nh_mask,
    const unsigned char* __restrict__ wfrag,
    const unsigned char* __restrict__ kvws,
    const float* __restrict__ ln_q_s, const float* __restrict__ ln_q_b,
    const float* __restrict__ bq, const float* __restrict__ b_out,
    const float* __restrict__ gamma, const float* __restrict__ ln_m_s,
    const float* __restrict__ ln_m_b, const float* __restrict__ bm,
    const float* __restrict__ b1, const float* __restrict__ b2,
    const float* __restrict__ gmlp, float* __restrict__ out) {
  extern __shared__ __align__(16) unsigned char smem[];
  const int tid = threadIdx.x, l = tid & 63, wv = tid >> 6;
  const int lo = l & 15, g = l >> 4;
  unsigned char* Wlds = smem;                       // 98304 B: 6 x 16 KB fp8
  unsigned char* X    = smem + 98304 + wv * 3328;   // 2048 B: [16 q][128 c] swz / VT overlay
  unsigned char* KP   = X + 2048;                   // 1280 B: K rows / P overlay

  // ---- one-time cooperative weight stage (96 KB), single barrier
  for (int r = 0; r < 8; ++r) {
    int off = (r * 12 + wv) * 1024;
    __builtin_amdgcn_global_load_lds(
        (const __attribute__((address_space(1))) unsigned int*)(wfrag + off + l * 16),
        (__attribute__((address_space(3))) unsigned int*)(Wlds + off), 16, 0, 0);
  }
  asm volatile("s_waitcnt vmcnt(0)" ::: "memory");
  __syncthreads();

  for (int it = 0; it < 2; ++it) {
    const int su = blockIdx.x * 24 + it * 12 + wv;   // < 24576
    const int t = su / SS, s = su - t * SS;
    const float* xqw = xq + (size_t)su * 2048;
    float* outw = out + (size_t)su * 2048;

    // ---- issue xq + kv loads, nh meta
    float4 xv[8];
#pragma unroll
    for (int mt = 0; mt < 8; ++mt)
      xv[mt] = *(const float4*)(xqw + lo * 128 + mt * 16 + g * 4);
    uint4 kvr[3];
#pragma unroll
    for (int j = 0; j < 3; ++j) {
      int idx = j * 64 + l;
      if (idx < 144) {
        int jrow = nh_idx[s * 9 + (idx >> 4)];
        kvr[j] = *(const uint4*)(kvws + ((size_t)(t * SS + jrow)) * 256 + (idx & 15) * 16);
      }
    }
    float sbias[4];
#pragma unroll
    for (int e = 0; e < 4; ++e) {
      int n = g * 4 + e;
      sbias[e] = (n < 9) ? (nh_mask[s * 9 + n] ? 0.0f : -1e9f) : -1e9f;
    }

    // ---- LN1 -> X (fp8). lane owns row lo, channels mt*16+g*4+e.
    {
      float sum = 0.f, sq = 0.f;
#pragma unroll
      for (int mt = 0; mt < 8; ++mt) {
        sum += xv[mt].x + xv[mt].y + xv[mt].z + xv[mt].w;
        sq  += xv[mt].x*xv[mt].x + xv[mt].y*xv[mt].y + xv[mt].z*xv[mt].z + xv[mt].w*xv[mt].w;
      }
      sum += __shfl_xor(sum, 16); sum += __shfl_xor(sum, 32);
      sq  += __shfl_xor(sq, 16);  sq  += __shfl_xor(sq, 32);
      float mu = sum * (1.0f/128.f);
      float rs = rsqrtf(sq * (1.0f/128.f) - mu*mu + 1e-5f);
#pragma unroll
      for (int mt = 0; mt < 8; ++mt) {
        int c0 = mt * 16 + g * 4;
        float4 s4 = *(const float4*)(ln_q_s + c0);
        float4 b4 = *(const float4*)(ln_q_b + c0);
        *(unsigned*)(X + xoff(lo, c0)) = pk4_fp8(
            (xv[mt].x - mu) * rs * s4.x + b4.x,
            (xv[mt].y - mu) * rs * s4.y + b4.y,
            (xv[mt].z - mu) * rs * s4.z + b4.z,
            (xv[mt].w - mu) * rs * s4.w + b4.w);
      }
    }
    // ---- land K rows (fp8, chunk-swizzled with even mask so b128 stays intact)
#pragma unroll
    for (int j = 0; j < 3; ++j) {
      int idx = j * 64 + l;
      if (idx < 144 && (idx & 15) < 8) {
        int n = idx >> 4, ch = idx & 15;
        *(uint4*)(KP + n * 128 + (((ch * 2) ^ (n & 14)) << 3)) = kvr[j];
      }
    }
    wave_sync();

    // q  = y1 @ Wq + bq
    mmF<0>(X, Wlds + 0 * 16384, bq, lo, g, l);
    wave_sync();
    // qh = (q @ Wa_q) * 1/sqrt(32)
    mmF<4>(X, Wlds + 1 * 16384, nullptr, lo, g, l);
    wave_sync();

    // ---- attention (all-MFMA, wave-local)
    {
      int nc = lo > 8 ? 8 : lo;   // K-row clamp; garbage killed by sbias
      long long ka[4], qb[4];
#pragma unroll
      for (int h = 0; h < 4; ++h) {
        ka[h] = *(const long long*)(KP + nc * 128 + ((((h * 4 + g) ^ (nc & 14))) << 3));
        qb[h] = *(const long long*)(X + xoff(lo, h * 32 + g * 8));
      }
      f32x4 st[4];
#pragma unroll
      for (int h = 0; h < 4; ++h) st[h] = mfma8(ka[h], qb[h], f32x4_zero());
      wave_sync();   // K/qh reads retired; KP/X reusable
      // softmax over n (in-lane e + shfl over g); P -> KP (fp8), zeros for n>=9
#pragma unroll
      for (int h = 0; h < 4; ++h) {
        float p0 = st[h][0] + sbias[0], p1 = st[h][1] + sbias[1];
        float p2 = st[h][2] + sbias[2], p3 = st[h][3] + sbias[3];
        float m = fmaxf(fmaxf(p0, p1), fmaxf(p2, p3));
        m = fmaxf(m, __shfl_xor(m, 16)); m = fmaxf(m, __shfl_xor(m, 32));
        p0 = __expf(p0 - m); p1 = __expf(p1 - m);
        p2 = __expf(p2 - m); p3 = __expf(p3 - m);
        float ss = p0 + p1 + p2 + p3;
        ss += __shfl_xor(ss, 16); ss += __shfl_xor(ss, 32);
        float inv = 1.0f / ss;
        *(unsigned*)(KP + h * 256 + lo * 16 + g * 4) =
            pk4_fp8(p0 * inv, p1 * inv, p2 * inv, p3 * inv);
      }
      // zero VT (X region) then land V as VT[d][16 n] (NaN-safe padding)
      {
        uint4 z; z.x = 0u; z.y = 0u; z.z = 0u; z.w = 0u;
        *(uint4*)(X + l * 32) = z;
        *(uint4*)(X + l * 32 + 16) = z;
      }
      wave_sync();
#pragma unroll
      for (int j = 0; j < 3; ++j) {
        int idx = j * 64 + l;
        if (idx < 144 && (idx & 15) >= 8) {
          int n = idx >> 4, d0 = ((idx & 15) - 8) * 16;
          unsigned w0 = kvr[j].x, w1 = kvr[j].y, w2 = kvr[j].z, w3 = kvr[j].w;
#pragma unroll
          for (int dd = 0; dd < 16; ++dd) {
            unsigned wsel = (dd < 4) ? w0 : (dd < 8) ? w1 : (dd < 12) ? w2 : w3;
            X[(d0 + dd) * 16 + n] = (unsigned char)((wsel >> ((dd & 3) * 8)) & 0xFF);
          }
        }
      }
      wave_sync();
      // PV: A = V^T (VT), B = P; 8 MFMA
      long long pbh[4];
#pragma unroll
      for (int h = 0; h < 4; ++h)
        pbh[h] = (g < 2) ? *(const long long*)(KP + h * 256 + lo * 16 + g * 8) : 0LL;
      f32x4 oacc[8];
#pragma unroll
      for (int mt = 0; mt < 8; ++mt) {
        long long va = (g < 2) ? *(const long long*)(X + (mt * 16 + lo) * 16 + g * 8) : 0LL;
        oacc[mt] = mfma8(va, pbh[mt >> 1], f32x4_zero());
      }
      wave_sync();   // VT reads done -> overwrite X with ao
#pragma unroll
      for (int mt = 0; mt < 8; ++mt)
        *(unsigned*)(X + xoff(lo, mt * 16 + g * 4)) =
            pk4_fp8(oacc[mt][0], oacc[mt][1], oacc[mt][2], oacc[mt][3]);
      wave_sync();
    }

    // x2 = xq + gamma*(ao @ W_out + b_out)  (fp32 regs)
    f32x4 x2[8];
    mmF_x2(X, Wlds + 2 * 16384, b_out, xqw, gamma, x2, lo, g, l);
    wave_sync();

    // ---- LN2 on x2 regs -> y2 -> X (fp8)
    {
      float sum = 0.f, sq = 0.f;
#pragma unroll
      for (int mt = 0; mt < 8; ++mt) {
        sum += x2[mt][0] + x2[mt][1] + x2[mt][2] + x2[mt][3];
        sq  += x2[mt][0]*x2[mt][0] + x2[mt][1]*x2[mt][1]
             + x2[mt][2]*x2[mt][2] + x2[mt][3]*x2[mt][3];
      }
      sum += __shfl_xor(sum, 16); sum += __shfl_xor(sum, 32);
      sq  += __shfl_xor(sq, 16);  sq  += __shfl_xor(sq, 32);
      float mu = sum * (1.0f/128.f);
      float rs = rsqrtf(sq * (1.0f/128.f) - mu*mu + 1e-5f);
#pragma unroll
      for (int mt = 0; mt < 8; ++mt) {
        int c0 = mt * 16 + g * 4;
        float4 s4 = *(const float4*)(ln_m_s + c0);
        float4 b4 = *(const float4*)(ln_m_b + c0);
        *(unsigned*)(X + xoff(lo, c0)) = pk4_fp8(
            (x2[mt][0] - mu) * rs * s4.x + b4.x,
            (x2[mt][1] - mu) * rs * s4.y + b4.y,
            (x2[mt][2] - mu) * rs * s4.z + b4.z,
            (x2[mt][3] - mu) * rs * s4.w + b4.w);
      }
    }
    wave_sync();

    // h1 = y2 @ Wm + bm
    mmF<0>(X, Wlds + 3 * 16384, bm, lo, g, l);
    wave_sync();
    // g1 = gelu(h1 @ W1 + b1)
    mmF<1>(X, Wlds + 4 * 16384, b1, lo, g, l);
    wave_sync();
    // m = g1 @ W2 + b2; out = x2 + gmlp*m
    mmF_out(X, Wlds + 5 * 16384, b2, gmlp, x2, outw, lo, g, l);
    wave_sync();
  }
}

// ---------------------------------------------------------------------------
extern "C" void kernel_launch(void* const* d_in, const int* in_sizes, int n_in,
                              void* d_out, int out_size, void* d_ws, size_t ws_size,
                              hipStream_t stream) {
  const float* x_q     = (const float*)d_in[0];
  const float* x_kv    = (const float*)d_in[1];
  const int* nh_idx    = (const int*)d_in[2];
  const unsigned char* nh_mask = (const unsigned char*)d_in[3];
  const float* ln_q_s  = (const float*)d_in[4];
  const float* ln_q_b  = (const float*)d_in[5];
  const float* Wq      = (const float*)d_in[6];
  const float* bq      = (const float*)d_in[7];
  const float* ln_kv_s = (const float*)d_in[8];
  const float* ln_kv_b = (const float*)d_in[9];
  const float* Wkv     = (const float*)d_in[10];
  const float* bkv     = (const float*)d_in[11];
  const float* Wa_q    = (const float*)d_in[12];
  const float* W_out   = (const float*)d_in[13];
  const float* b_out   = (const float*)d_in[14];
  const float* gamma   = (const float*)d_in[15];
  const float* ln_m_s  = (const float*)d_in[16];
  const float* ln_m_b  = (const float*)d_in[17];
  const float* Wm      = (const float*)d_in[18];
  const float* bm      = (const float*)d_in[19];
  const float* W1      = (const float*)d_in[20];
  const float* b1      = (const float*)d_in[21];
  const float* W2      = (const float*)d_in[22];
  const float* b2      = (const float*)d_in[23];
  const float* gmlp    = (const float*)d_in[24];

  unsigned char* wfrag = (unsigned char*)d_ws;          // 98304 B fp8 weight frags
  unsigned char* kvws  = wfrag + 98304;                 // 24576*256 fp8 kv

  prep_weights<<<384, 256, 0, stream>>>(Wq, Wa_q, W_out, Wm, W1, W2, wfrag);
  kv_proj<<<1536, 256, 0, stream>>>(x_kv, ln_kv_s, ln_kv_b, Wkv, bkv, kvws);

  const int lds_bytes = 98304 + 12 * 3328;   // 138240
  (void)hipFuncSetAttribute((const void*)fused_main,
                            hipFuncAttributeMaxDynamicSharedMemorySize, lds_bytes);
  fused_main<<<1024, 768, lds_bytes, stream>>>(
      x_q, nh_idx, nh_mask, wfrag, kvws, ln_q_s, ln_q_b, bq, b_out, gamma,
      ln_m_s, ln_m_b, bm, b1, b2, gmlp, (float*)d_out);
}